// Round 11
// baseline (6154.660 us; speedup 1.0000x reference)
//
#include <hip/hip_runtime.h>
#include <cstdint>
#include <cstddef>

// ---------------------------------------------------------------- sizes
#define LT 512
#define BB 128
#define DD 512
#define HH 1024
#define HD 1536
#define MT (LT*BB)   // 65536

typedef __bf16 bf16;
typedef __bf16 bf16x8 __attribute__((ext_vector_type(8)));
typedef __bf16 bf16x4 __attribute__((ext_vector_type(4)));
typedef float  f32x4  __attribute__((ext_vector_type(4)));

// ---------------------------------------------------------------- ws layout (bytes)
#define O_WZR 0u                 // bf16 [2048][1536]
#define O_WHR 6291456u           // bf16 [1024][1024]
#define O_WXH 8388608u           // bf16 [1024][512]
#define O_XB  9437184u           // bf16 [65536][512]
#define O_HB  76546048u          // bf16 [128][1024]   h (scoped-coherent)
#define O_RHB 76808192u          // bf16 [128][1024]   r*h
#define O_ZB  77070336u          // f32  [128][1024]   z gate
#define O_BAR 77594624u          // 8 groups x 8KB {vote slots, cntA x2} (memset)
#define O_FLG 77660160u          // 8 groups x 32KB flag bytes [2][512][32] (NOT memset)
#define WS_NEED 77922304u

#define WAIT_VM0()  asm volatile("s_waitcnt vmcnt(0)" ::: "memory")
#define WAIT_VM4()  asm volatile("s_waitcnt vmcnt(4)" ::: "memory")
#define WAIT_VM12() asm volatile("s_waitcnt vmcnt(12)" ::: "memory")
#define SCHED0()    __builtin_amdgcn_sched_barrier(0)
#define L1_INV()    asm volatile("buffer_inv sc0" ::: "memory")   // L1-only flash inv

// ---------------------------------------------------------------- scoped data access
// L=1: XCD-local (sc0; write-through to XCD L2; reads fresh after L1_INV).
// L=0: IF point (sc0 sc1) — R3-proven. Plain (p-suffix): normal cached,
// via asm so issue ORDER vs other asm loads is pinned (counted vmcnt waits).
template<int L> __device__ __forceinline__ f32x4 ld16s(const void* p) {
  f32x4 r;
  if constexpr (L) asm volatile("global_load_dwordx4 %0, %1, off sc0"     : "=&v"(r) : "v"(p) : "memory");
  else             asm volatile("global_load_dwordx4 %0, %1, off sc0 sc1" : "=&v"(r) : "v"(p) : "memory");
  return r;
}
template<int L> __device__ __forceinline__ float ld4s(const void* p) {
  float r;
  if constexpr (L) asm volatile("global_load_dword %0, %1, off sc0"     : "=&v"(r) : "v"(p) : "memory");
  else             asm volatile("global_load_dword %0, %1, off sc0 sc1" : "=&v"(r) : "v"(p) : "memory");
  return r;
}
template<int L> __device__ __forceinline__ unsigned ld2s(const void* p) {
  unsigned r;
  if constexpr (L) asm volatile("global_load_ushort %0, %1, off sc0"     : "=&v"(r) : "v"(p) : "memory");
  else             asm volatile("global_load_ushort %0, %1, off sc0 sc1" : "=&v"(r) : "v"(p) : "memory");
  return r;
}
template<int L> __device__ __forceinline__ void st4s(float* p, float v) {
  if constexpr (L) asm volatile("global_store_dword %0, %1, off sc0"     :: "v"(p), "v"(v) : "memory");
  else             asm volatile("global_store_dword %0, %1, off sc0 sc1" :: "v"(p), "v"(v) : "memory");
}
template<int L> __device__ __forceinline__ void st2s(bf16* p, unsigned v) {
  if constexpr (L) asm volatile("global_store_short %0, %1, off sc0"     :: "v"(p), "v"(v) : "memory");
  else             asm volatile("global_store_short %0, %1, off sc0 sc1" :: "v"(p), "v"(v) : "memory");
}
__device__ __forceinline__ f32x4 ld16p(const void* p) {
  f32x4 r;
  asm volatile("global_load_dwordx4 %0, %1, off" : "=&v"(r) : "v"(p) : "memory");
  return r;
}
__device__ __forceinline__ float ld4p(const void* p) {
  float r;
  asm volatile("global_load_dword %0, %1, off" : "=&v"(r) : "v"(p) : "memory");
  return r;
}
__device__ __forceinline__ void st_flag(unsigned char* p, unsigned v) {
  asm volatile("global_store_byte %0, %1, off sc0" :: "v"(p), "v"(v) : "memory");
}
__device__ __forceinline__ unsigned ld_flag(const unsigned char* p) {
  unsigned r;
  asm volatile("global_load_ubyte %0, %1, off sc0\n\ts_waitcnt vmcnt(0)"
               : "=&v"(r) : "v"(p) : "memory");
  return r;
}
__device__ __forceinline__ unsigned bf16_bits(float f) {
  bf16 b = (bf16)f;
  return (unsigned)__builtin_bit_cast(unsigned short, b);
}
__device__ __forceinline__ float bits_to_f32(unsigned u16) {
  return __builtin_bit_cast(float, u16 << 16);
}

// ---------------------------------------------------------------- small prep kernels
__global__ void k_cvt(const float* __restrict__ s, bf16* __restrict__ d, int n8) {
  int i = blockIdx.x*256 + threadIdx.x;
  if (i >= n8) return;
  const float4* p = (const float4*)s + (size_t)i*2;
  float4 a = p[0], b = p[1];
  bf16x8 v = {(bf16)a.x,(bf16)a.y,(bf16)a.z,(bf16)a.w,(bf16)b.x,(bf16)b.y,(bf16)b.z,(bf16)b.w};
  *((bf16x8*)d + i) = v;
}

__global__ void k_split_wh(const float* __restrict__ Wh, bf16* __restrict__ whr, bf16* __restrict__ wxh) {
  int i = blockIdx.x*256 + threadIdx.x;
  if (i >= 1024*192) return;
  int row = i / 192, c8 = (i % 192)*8;
  const float4* p = (const float4*)(Wh + (size_t)row*HD + c8);
  float4 a = p[0], b = p[1];
  bf16x8 v = {(bf16)a.x,(bf16)a.y,(bf16)a.z,(bf16)a.w,(bf16)b.x,(bf16)b.y,(bf16)b.z,(bf16)b.w};
  bf16* dptr = (c8 < HH) ? (whr + (size_t)row*HH + c8) : (wxh + (size_t)row*DD + (c8 - HH));
  *(bf16x8*)dptr = v;
}

__global__ void k_init_h(const float* __restrict__ h0, bf16* __restrict__ hb) {
  int i = blockIdx.x*256 + threadIdx.x;
  float4 a = ((const float4*)h0)[i];
  bf16x4 v = {(bf16)a.x,(bf16)a.y,(bf16)a.z,(bf16)a.w};
  *((bf16x4*)hb + i) = v;
}

// ---------------------------------------------------------------- Xh GEMM: out = x @ Wxh^T + b_h
__global__ __launch_bounds__(256) void k_gemm_xh(
    const bf16* __restrict__ xb, const bf16* __restrict__ wxh,
    const float* __restrict__ bh, float* __restrict__ out)
{
  __shared__ char As[16384];
  __shared__ char Bs[16384];
  const int bid = blockIdx.x;
  const int nt8 = bid & 7, mtb = bid >> 3;
  const int tid = threadIdx.x;
  const int lane = tid & 63, wv = tid >> 6;
  const int l15 = lane & 15, q = lane >> 4;
  const int wm = wv >> 1, wn = wv & 1;
  f32x4 acc[4][4] = {};
  const char* Ab = (const char*)(xb + (size_t)mtb*128*DD);
  const char* Bb = (const char*)(wxh + (size_t)nt8*128*DD);
  const int crow = tid >> 3, ccb = (tid & 7)*16;
  const int cdst = crow*128 + (ccb ^ ((crow & 7) << 4));
  for (int kt = 0; kt < 8; ++kt) {
    __syncthreads();
    #pragma unroll
    for (int i = 0; i < 4; ++i) {
      *(uint4*)(As + cdst + i*4096) = *(const uint4*)(Ab + (size_t)(crow + i*32)*1024 + kt*128 + ccb);
      *(uint4*)(Bs + cdst + i*4096) = *(const uint4*)(Bb + (size_t)(crow + i*32)*1024 + kt*128 + ccb);
    }
    __syncthreads();
    #pragma unroll
    for (int ks = 0; ks < 2; ++ks) {
      bf16x8 af[4], bfr[4];
      #pragma unroll
      for (int m4 = 0; m4 < 4; ++m4) {
        int row = wm*64 + m4*16 + l15, cb = ks*64 + 16*q;
        af[m4] = *(const bf16x8*)(As + row*128 + (cb ^ ((row&7)<<4)));
      }
      #pragma unroll
      for (int n4 = 0; n4 < 4; ++n4) {
        int row = wn*64 + n4*16 + l15, cb = ks*64 + 16*q;
        bfr[n4] = *(const bf16x8*)(Bs + row*128 + (cb ^ ((row&7)<<4)));
      }
      #pragma unroll
      for (int m4 = 0; m4 < 4; ++m4)
        #pragma unroll
        for (int n4 = 0; n4 < 4; ++n4)
          acc[m4][n4] = __builtin_amdgcn_mfma_f32_16x16x32_bf16(af[m4], bfr[n4], acc[m4][n4], 0, 0, 0);
    }
  }
  const int jb = nt8*128 + wn*64;
  const size_t mb = (size_t)mtb*128 + wm*64;
  #pragma unroll
  for (int n4 = 0; n4 < 4; ++n4) {
    int j = jb + n4*16 + l15;
    float bias = bh[j];
    #pragma unroll
    for (int m4 = 0; m4 < 4; ++m4)
      #pragma unroll
      for (int e = 0; e < 4; ++e) {
        size_t m = mb + m4*16 + 4*q + e;
        out[m*HH + j] = acc[m4][n4][e] + bias;
      }
  }
}

// ---------------------------------------------------------------- recurrent kernel
// 256 blocks x 512 threads; group g = bid&7 = one XCD (vote-verified).
// R10 machinery (local sc0 data + flag barriers + L1_INV poll + IF fallback)
// plus: cross-barrier x/xh prefetch with counted vmcnt waits, and folded
// barrier entry (only the 2 storing waves drain; LDS handshake wv1->wv0).
struct Frags { bf16x8 zr[4][2]; bf16x8 h[8]; };

template<int L>
__device__ __forceinline__ void tloop(const Frags& F, char* ldsW, char* scr,
    const bf16* __restrict__ xb, float* __restrict__ out,
    bf16* __restrict__ hb, bf16* __restrict__ rhb, float* __restrict__ zbuf,
    unsigned* cnt1A, unsigned* cnt2A, unsigned char* flg1, unsigned char* flg2,
    int voteok, int g, int sb, int ch, int kh, int tid, int lane, int wv,
    const float (&bias)[2], float (&hreg)[4])
{
  __shared__ unsigned s_done[2];
  const int l15 = lane & 15, q = lane >> 4;
  const bf16* hrow = hb  + (size_t)(g*16 + l15)*HH;
  const bf16* rrow = rhb + (size_t)(g*16 + l15)*HH;
  const int kh384 = kh*384, kh256 = kh*256;
  const int jown = sb*32 + ch*16 + l15;
  int use_local = L ? voteok : 0;
  if (tid == 0) { s_done[0] = 0; s_done[1] = 0; }   // ordered by first reduce-sync

  // persistent A-operand regs; x-slots (kabs>=HH) prefilled for t=0
  f32x4 ab[12];
  {
    const bf16* xrow0 = xb + (size_t)(g*16 + l15)*DD;
    #pragma unroll
    for (int kk = 0; kk < 12; ++kk) {
      int kabs = kh384 + kk*32;
      if (kabs >= HH) ab[kk] = ld16p(xrow0 + (kabs - HH) + 8*q);
    }
  }

  for (int t = 0; t < LT; ++t) {
    float xh[4];
    // ---------------- phase 1: z (sb<16) or r preacts, K=1536 ----------------
    {
      #pragma unroll
      for (int kk = 0; kk < 12; ++kk) {          // h-part loads (x-part prefetched)
        int kabs = kh384 + kk*32;
        if (kabs < HH) ab[kk] = ld16s<L>(hrow + kabs + 8*q);
      }
      unsigned hv[2][4];
      if (sb >= 16 && kh == 0) {                 // r-block: cross-block h
        #pragma unroll
        for (int nt = 0; nt < 2; ++nt) {
          int cr = sb*64 - HH + ch*32 + nt*16 + l15;
          #pragma unroll
          for (int e = 0; e < 4; ++e)
            hv[nt][e] = ld2s<L>(hb + (size_t)(g*16 + 4*q + e)*HH + cr);
        }
      }
      if (kh == 0) {                             // prefetch Xh for phase 2 (newest 4)
        #pragma unroll
        for (int e = 0; e < 4; ++e)
          xh[e] = ld4p(out + (size_t)t*(BB*HH) + (size_t)(g*16 + 4*q + e)*HH + jown);
      }
      if (kh == 0) { WAIT_VM4(); } else { WAIT_VM0(); }
      SCHED0();
      f32x4 a0 = {}, a1 = {};
      #pragma unroll
      for (int kk = 0; kk < 12; ++kk) {
        bf16x8 a = __builtin_bit_cast(bf16x8, ab[kk]);
        bf16x8 b0, b1;
        if (kk < 8) {
          b0 = *(const bf16x8*)(ldsW + (ch*32      + l15)*2064 + kh*512 + kk*64 + 16*q);
          b1 = *(const bf16x8*)(ldsW + (ch*32 + 16 + l15)*2064 + kh*512 + kk*64 + 16*q);
        } else { b0 = F.zr[kk-8][0]; b1 = F.zr[kk-8][1]; }
        a0 = __builtin_amdgcn_mfma_f32_16x16x32_bf16(a, b0, a0, 0, 0, 0);
        a1 = __builtin_amdgcn_mfma_f32_16x16x32_bf16(a, b1, a1, 0, 0, 0);
      }
      if (kh) {
        int s = ((kh-1)*2 + ch)*2;
        *(f32x4*)(scr + (s+0)*1024 + lane*16) = a0;
        *(f32x4*)(scr + (s+1)*1024 + lane*16) = a1;
      }
      __syncthreads();                           // reduce-sync (doubles as entry)
      if (kh == 0) {
        #pragma unroll
        for (int k2 = 0; k2 < 3; ++k2) {
          int s = (k2*2 + ch)*2;
          a0 += *(const f32x4*)(scr + (s+0)*1024 + lane*16);
          a1 += *(const f32x4*)(scr + (s+1)*1024 + lane*16);
        }
        if (sb < 16) {                           // z block
          #pragma unroll
          for (int nt = 0; nt < 2; ++nt) {
            f32x4 ac = nt ? a1 : a0;
            int c = sb*64 + ch*32 + nt*16 + l15;
            #pragma unroll
            for (int e = 0; e < 4; ++e) {
              int m = g*16 + 4*q + e;
              float gate = 1.f/(1.f + __expf(-(ac[e] + bias[nt])));
              st4s<L>(zbuf + (size_t)m*HH + c, gate);
            }
          }
        } else {                                 // r block
          #pragma unroll
          for (int nt = 0; nt < 2; ++nt) {
            f32x4 ac = nt ? a1 : a0;
            int cr = sb*64 - HH + ch*32 + nt*16 + l15;
            #pragma unroll
            for (int e = 0; e < 4; ++e) {
              int m = g*16 + 4*q + e;
              float gate = 1.f/(1.f + __expf(-(ac[e] + bias[nt])));
              st2s<L>(rhb + (size_t)m*HH + cr, bf16_bits(gate * bits_to_f32(hv[nt][e])));
            }
          }
        }
        WAIT_VM0();                              // my stores at scope point
        if (ch == 1) {
          if (lane == 0)
            __hip_atomic_fetch_add(&s_done[0], 1u, __ATOMIC_RELAXED, __HIP_MEMORY_SCOPE_WORKGROUP);
        } else {
          if (lane == 0) {
            int gd = 1<<22;                      // LDS handshake: wv1 drained?
            while (!__hip_atomic_load(&s_done[0], __ATOMIC_RELAXED, __HIP_MEMORY_SCOPE_WORKGROUP) && --gd) {}
            __hip_atomic_store(&s_done[0], 0u, __ATOMIC_RELAXED, __HIP_MEMORY_SCOPE_WORKGROUP);
            __hip_atomic_fetch_add(cnt1A, 1u, __ATOMIC_RELAXED, __HIP_MEMORY_SCOPE_AGENT);
            if (L && voteok) st_flag(flg1 + t*32 + sb, 1u);
          }
          int done = 0;
          if (use_local && t >= 2) {
            int gd = 1500;
            while (gd--) {
              L1_INV();
              unsigned ok = 1u;
              if (lane < 32) ok = ld_flag(flg1 + t*32 + lane);
              if (__ballot(ok != 0u) == ~0ull) { done = 1; break; }
            }
            if (!done) use_local = 0;
          }
          if (!done && lane == 0) {
            unsigned tgt = 32u*(unsigned)(t+1);
            int gd = 60000;
            while (__hip_atomic_load(cnt1A, __ATOMIC_RELAXED, __HIP_MEMORY_SCOPE_AGENT) < tgt
                   && --gd) __builtin_amdgcn_s_sleep(2);
          }
          L1_INV();
        }
      }
      __syncthreads();                           // release
    }
    // ---------------- phase 2: h_tilde + combine, K=1024 ----------------
    {
      f32x4 rb[8];
      #pragma unroll
      for (int kk = 0; kk < 8; ++kk)
        rb[kk] = ld16s<L>(rrow + kh256 + kk*32 + 8*q);
      float zv[4];
      if (kh == 0) {
        #pragma unroll
        for (int e = 0; e < 4; ++e)
          zv[e] = ld4s<L>(zbuf + (size_t)(g*16 + 4*q + e)*HH + jown);
      }
      {                                          // prefetch x for step t+1 -> ab x-slots
        int tn = (t+1 < LT) ? t+1 : t;
        const bf16* xrow_n = xb + (size_t)(tn*BB + g*16 + l15)*DD;
        #pragma unroll
        for (int kk = 0; kk < 12; ++kk) {
          int kabs = kh384 + kk*32;
          if (kabs >= HH) ab[kk] = ld16p(xrow_n + (kabs - HH) + 8*q);
        }
      }
      if      (kh == 3) { WAIT_VM12(); }         // leave 12 x-prefetch in flight
      else if (kh == 2) { WAIT_VM4(); }          // leave 4 x-prefetch in flight
      else if (kh == 0) { WAIT_VM4(); }          // leave 4 zv in flight (rb drained)
      else              { WAIT_VM0(); }
      SCHED0();
      f32x4 acc = {};
      #pragma unroll
      for (int kk = 0; kk < 8; ++kk)
        acc = __builtin_amdgcn_mfma_f32_16x16x32_bf16(
            __builtin_bit_cast(bf16x8, rb[kk]), F.h[kk], acc, 0, 0, 0);
      if (kh) *(f32x4*)(scr + ((kh-1)*2 + ch)*1024 + lane*16) = acc;
      __syncthreads();                           // reduce-sync
      if (kh == 0) {
        WAIT_VM0(); SCHED0();                    // zv (+leftovers) done
        #pragma unroll
        for (int k2 = 0; k2 < 3; ++k2)
          acc += *(const f32x4*)(scr + (k2*2 + ch)*1024 + lane*16);
        #pragma unroll
        for (int e = 0; e < 4; ++e) {
          int m = g*16 + 4*q + e;
          size_t idx = (size_t)m*HH + jown;
          size_t oidx = (size_t)t*(BB*HH) + idx;
          float ht = tanhf(acc[e] + xh[e]);      // xh prefetched in phase 1
          float hn = hreg[e] + zv[e]*(ht - hreg[e]);
          out[oidx] = hn;                        // plain store (block-private slot)
          hreg[e] = hn;
          st2s<L>(hb + idx, bf16_bits(hn));
        }
        WAIT_VM0();
        if (ch == 1) {
          if (lane == 0)
            __hip_atomic_fetch_add(&s_done[1], 1u, __ATOMIC_RELAXED, __HIP_MEMORY_SCOPE_WORKGROUP);
        } else {
          if (lane == 0) {
            int gd = 1<<22;
            while (!__hip_atomic_load(&s_done[1], __ATOMIC_RELAXED, __HIP_MEMORY_SCOPE_WORKGROUP) && --gd) {}
            __hip_atomic_store(&s_done[1], 0u, __ATOMIC_RELAXED, __HIP_MEMORY_SCOPE_WORKGROUP);
            __hip_atomic_fetch_add(cnt2A, 1u, __ATOMIC_RELAXED, __HIP_MEMORY_SCOPE_AGENT);
            if (L && voteok) st_flag(flg2 + t*32 + sb, 1u);
          }
          int done = 0;
          if (use_local && t >= 2) {
            int gd = 1500;
            while (gd--) {
              L1_INV();
              unsigned ok = 1u;
              if (lane < 32) ok = ld_flag(flg2 + t*32 + lane);
              if (__ballot(ok != 0u) == ~0ull) { done = 1; break; }
            }
            if (!done) use_local = 0;
          }
          if (!done && lane == 0) {
            unsigned tgt = 32u*(unsigned)(t+1);
            int gd = 60000;
            while (__hip_atomic_load(cnt2A, __ATOMIC_RELAXED, __HIP_MEMORY_SCOPE_AGENT) < tgt
                   && --gd) __builtin_amdgcn_s_sleep(2);
          }
          L1_INV();
        }
      }
      __syncthreads();                           // release
      if (L && tid == 0 && voteok && t + 2 < LT) {  // self-clear own t+2 flags
        st_flag(flg1 + (t+2)*32 + sb, 0u);
        st_flag(flg2 + (t+2)*32 + sb, 0u);
      }
    }
  }
}

__global__ __launch_bounds__(512, 2) void k_gru(
    const bf16* __restrict__ Wzr, const bf16* __restrict__ Whr,
    const bf16* __restrict__ xb, const float* __restrict__ h0,
    const float* __restrict__ bz, const float* __restrict__ br,
    float* __restrict__ out,
    bf16* __restrict__ hb, bf16* __restrict__ rhb, float* __restrict__ zbuf,
    unsigned* __restrict__ bar, unsigned char* __restrict__ flg)
{
  extern __shared__ char smem[];
  char* ldsW = smem;            // W_zr LDS part: 64 cols x 2064B
  char* scr  = smem + 132096;   // 12KB kh-reduce scratch
  __shared__ int s_mode;

  const int tid = threadIdx.x, bid = blockIdx.x;
  const int lane = tid & 63, wv = tid >> 6;
  const int l15 = lane & 15, q = lane >> 4;
  const int g = bid & 7, sb = bid >> 3;
  const int ch = wv & 1, kh = wv >> 1;
  unsigned* grp   = bar + (size_t)g*2048;
  unsigned* cnt1A = grp + 40;
  unsigned* cnt2A = grp + 48;
  unsigned char* flg1 = flg + (size_t)g*32768;
  unsigned char* flg2 = flg + (size_t)g*32768 + 16384;

  // stage LDS weights: cols [sb*64,+64), per-kh k-subrange [kh*384, +256)
  #pragma unroll
  for (int i = 0; i < 16; ++i) {
    int ci = tid + i*512;
    int row = ci >> 7, c = ci & 127;
    int le = c*8, khs = le >> 8, rem = le & 255;
    *(uint4*)(ldsW + row*2064 + c*16) =
      *(const uint4*)(Wzr + (size_t)(sb*64 + row)*HD + khs*384 + rem);
  }
  Frags F;
  #pragma unroll
  for (int i = 0; i < 4; ++i)
    #pragma unroll
    for (int nt = 0; nt < 2; ++nt)
      F.zr[i][nt] = *(const bf16x8*)(Wzr + (size_t)(sb*64 + ch*32 + nt*16 + l15)*HD
                                     + kh*384 + (8+i)*32 + 8*q);
  #pragma unroll
  for (int kk = 0; kk < 8; ++kk)
    F.h[kk] = *(const bf16x8*)(Whr + (size_t)(sb*32 + ch*16 + l15)*HH + kh*256 + kk*32 + 8*q);

  float bias[2];
  #pragma unroll
  for (int nt = 0; nt < 2; ++nt) {
    int c = sb*64 + ch*32 + nt*16 + l15;
    bias[nt] = (sb < 16) ? bz[c] : br[c - HH];
  }
  float hreg[4];
  const int jown = sb*32 + ch*16 + l15;
  #pragma unroll
  for (int e = 0; e < 4; ++e)
    hreg[e] = h0[(size_t)(g*16 + 4*q + e)*HH + jown];

  // XCD vote (bounded; perf-only — IF fallback always correct)
  if (tid == 0) {
    int xcc;
    asm("s_getreg_b32 %0, hwreg(HW_REG_XCC_ID)" : "=s"(xcc));
    __hip_atomic_store(&grp[sb], (unsigned)(xcc + 1), __ATOMIC_RELAXED, __HIP_MEMORY_SCOPE_AGENT);
    unsigned first = 0; int ok = 1;
    long budget = 200000;
    for (int i = 0; i < 32; ++i) {
      unsigned v = 0;
      while (budget > 0) {
        v = __hip_atomic_load(&grp[i], __ATOMIC_RELAXED, __HIP_MEMORY_SCOPE_AGENT);
        if (v) break;
        --budget; __builtin_amdgcn_s_sleep(8);
      }
      if (!v) { ok = 0; break; }
      if (i == 0) first = v;
      else if (v != first) { ok = 0; break; }
    }
    s_mode = ok;
  }
  __syncthreads();
  int voteok = s_mode;

  if (voteok) tloop<1>(F, ldsW, scr, xb, out, hb, rhb, zbuf, cnt1A, cnt2A,
                       flg1, flg2, 1, g, sb, ch, kh, tid, lane, wv, bias, hreg);
  else        tloop<0>(F, ldsW, scr, xb, out, hb, rhb, zbuf, cnt1A, cnt2A,
                       flg1, flg2, 0, g, sb, ch, kh, tid, lane, wv, bias, hreg);
}

// ---------------------------------------------------------------- launch
extern "C" void kernel_launch(void* const* d_in, const int* in_sizes, int n_in,
                              void* d_out, int out_size, void* d_ws, size_t ws_size,
                              hipStream_t stream) {
  const float* x  = (const float*)d_in[0];
  const float* h0 = (const float*)d_in[1];
  const float* Wz = (const float*)d_in[2];
  const float* bz = (const float*)d_in[3];
  const float* Wr = (const float*)d_in[4];
  const float* br = (const float*)d_in[5];
  const float* Wh = (const float*)d_in[6];
  const float* bh = (const float*)d_in[7];
  float* out = (float*)d_out;
  char* ws = (char*)d_ws;
  if (ws_size < (size_t)WS_NEED) return;

  bf16*  wzr  = (bf16*) (ws + O_WZR);
  bf16*  whr  = (bf16*) (ws + O_WHR);
  bf16*  wxh  = (bf16*) (ws + O_WXH);
  bf16*  xbb  = (bf16*) (ws + O_XB);
  bf16*  hb   = (bf16*) (ws + O_HB);
  bf16*  rhb  = (bf16*) (ws + O_RHB);
  float* zbuf = (float*)(ws + O_ZB);
  unsigned* bar = (unsigned*)(ws + O_BAR);
  unsigned char* flg = (unsigned char*)(ws + O_FLG);

  hipMemsetAsync(bar, 0, 65536, stream);
  k_cvt<<<16384, 256, 0, stream>>>(x, xbb, MT*DD/8);
  k_cvt<<<768, 256, 0, stream>>>(Wz, wzr, HH*HD/8);
  k_cvt<<<768, 256, 0, stream>>>(Wr, wzr + (size_t)HH*HD, HH*HD/8);
  k_split_wh<<<768, 256, 0, stream>>>(Wh, whr, wxh);
  k_init_h<<<128, 256, 0, stream>>>(h0, hb);
  k_gemm_xh<<<4096, 256, 0, stream>>>(xbb, wxh, bh, out);

  hipFuncSetAttribute((const void*)k_gru, hipFuncAttributeMaxDynamicSharedMemorySize, 144384);
  k_gru<<<256, 512, 144384, stream>>>(wzr, whr, xbb, h0, bz, br, out, hb, rhb, zbuf, bar, flg);
}

// Round 12
// 4615.643 us; speedup vs baseline: 1.3334x; 1.3334x over previous
//
#include <hip/hip_runtime.h>
#include <cstdint>
#include <cstddef>

// ---------------------------------------------------------------- sizes
#define LT 512
#define BB 128
#define DD 512
#define HH 1024
#define HD 1536
#define MT (LT*BB)   // 65536

typedef __bf16 bf16;
typedef __bf16 bf16x8 __attribute__((ext_vector_type(8)));
typedef __bf16 bf16x4 __attribute__((ext_vector_type(4)));
typedef float  f32x4  __attribute__((ext_vector_type(4)));

// ---------------------------------------------------------------- ws layout (bytes)
#define O_WZR 0u                 // bf16 [2048][1536]
#define O_WHR 6291456u           // bf16 [1024][1024]
#define O_WXH 8388608u           // bf16 [1024][512]
#define O_XB  9437184u           // bf16 [65536][512]
#define O_HB  76546048u          // bf16 [128][1024]   h (scoped-coherent)
#define O_RHB 76808192u          // bf16 [128][1024]   r*h
#define O_BAR 77594624u          // 8 groups x 8KB {vote slots, cntA x2} (memset)
#define O_FLG 77660160u          // 8 groups x 32KB flag bytes [2][512][32] (NOT memset)
#define WS_NEED 77922304u

#define WAIT_VM0() asm volatile("s_waitcnt vmcnt(0)" ::: "memory")
#define SCHED0()   __builtin_amdgcn_sched_barrier(0)
#define L1_INV()   asm volatile("buffer_inv sc0" ::: "memory")   // L1-only flash inv

// ---------------------------------------------------------------- scoped data access
// L=1: XCD-local (sc0; write-through to XCD L2; reads fresh after L1_INV).
// L=0: IF point (sc0 sc1) — R3-proven.
template<int L> __device__ __forceinline__ f32x4 ld16s(const void* p) {
  f32x4 r;
  if constexpr (L) asm volatile("global_load_dwordx4 %0, %1, off sc0"     : "=&v"(r) : "v"(p) : "memory");
  else             asm volatile("global_load_dwordx4 %0, %1, off sc0 sc1" : "=&v"(r) : "v"(p) : "memory");
  return r;
}
template<int L> __device__ __forceinline__ unsigned ld2s(const void* p) {
  unsigned r;
  if constexpr (L) asm volatile("global_load_ushort %0, %1, off sc0"     : "=&v"(r) : "v"(p) : "memory");
  else             asm volatile("global_load_ushort %0, %1, off sc0 sc1" : "=&v"(r) : "v"(p) : "memory");
  return r;
}
template<int L> __device__ __forceinline__ void st2s(bf16* p, unsigned v) {
  if constexpr (L) asm volatile("global_store_short %0, %1, off sc0"     :: "v"(p), "v"(v) : "memory");
  else             asm volatile("global_store_short %0, %1, off sc0 sc1" :: "v"(p), "v"(v) : "memory");
}
__device__ __forceinline__ void st_flag(unsigned char* p, unsigned v) {
  asm volatile("global_store_byte %0, %1, off sc0" :: "v"(p), "v"(v) : "memory");
}
__device__ __forceinline__ unsigned ld_flag(const unsigned char* p) {
  unsigned r;
  asm volatile("global_load_ubyte %0, %1, off sc0\n\ts_waitcnt vmcnt(0)"
               : "=&v"(r) : "v"(p) : "memory");
  return r;
}
__device__ __forceinline__ unsigned bf16_bits(float f) {
  bf16 b = (bf16)f;
  return (unsigned)__builtin_bit_cast(unsigned short, b);
}
__device__ __forceinline__ float bits_to_f32(unsigned u16) {
  return __builtin_bit_cast(float, u16 << 16);
}

// ---------------------------------------------------------------- barrier (R10-proven, unchanged)
__device__ __forceinline__ void bar_sync(unsigned* cntA, unsigned char* flagst,
                                         int t, int voteok, int& use_local,
                                         unsigned tgtA, int tid, int lane, int wv, int sb) {
  WAIT_VM0();                       // my wave's data stores are at the scope point
  __syncthreads();                  // all waves drained + arrived
  if (tid == 0)
    __hip_atomic_fetch_add(cntA, 1u, __ATOMIC_RELAXED, __HIP_MEMORY_SCOPE_AGENT);
  if (wv == 0) {
    if (tid == 0 && voteok) st_flag(flagst + sb, 1u);
    int done = 0;
    if (use_local && t >= 2) {
      int gd = 1500;
      while (gd--) {
        L1_INV();
        unsigned ok = 1u;
        if (lane < 32) ok = ld_flag(flagst + lane);
        if (__ballot(ok != 0u) == ~0ull) { done = 1; break; }
      }
      if (!done) use_local = 0;     // demote: flags not visible at L2 either
    }
    if (!done && tid == 0) {
      int gd = 60000;
      while (__hip_atomic_load(cntA, __ATOMIC_RELAXED, __HIP_MEMORY_SCOPE_AGENT) < tgtA
             && --gd) __builtin_amdgcn_s_sleep(2);
    }
    L1_INV();                       // fresh per-CU L1 view for the whole block
  }
  __syncthreads();
}

// ---------------------------------------------------------------- small prep kernels
__global__ void k_cvt(const float* __restrict__ s, bf16* __restrict__ d, int n8) {
  int i = blockIdx.x*256 + threadIdx.x;
  if (i >= n8) return;
  const float4* p = (const float4*)s + (size_t)i*2;
  float4 a = p[0], b = p[1];
  bf16x8 v = {(bf16)a.x,(bf16)a.y,(bf16)a.z,(bf16)a.w,(bf16)b.x,(bf16)b.y,(bf16)b.z,(bf16)b.w};
  *((bf16x8*)d + i) = v;
}

__global__ void k_split_wh(const float* __restrict__ Wh, bf16* __restrict__ whr, bf16* __restrict__ wxh) {
  int i = blockIdx.x*256 + threadIdx.x;
  if (i >= 1024*192) return;
  int row = i / 192, c8 = (i % 192)*8;
  const float4* p = (const float4*)(Wh + (size_t)row*HD + c8);
  float4 a = p[0], b = p[1];
  bf16x8 v = {(bf16)a.x,(bf16)a.y,(bf16)a.z,(bf16)a.w,(bf16)b.x,(bf16)b.y,(bf16)b.z,(bf16)b.w};
  bf16* dptr = (c8 < HH) ? (whr + (size_t)row*HH + c8) : (wxh + (size_t)row*DD + (c8 - HH));
  *(bf16x8*)dptr = v;
}

__global__ void k_init_h(const float* __restrict__ h0, bf16* __restrict__ hb) {
  int i = blockIdx.x*256 + threadIdx.x;
  float4 a = ((const float4*)h0)[i];
  bf16x4 v = {(bf16)a.x,(bf16)a.y,(bf16)a.z,(bf16)a.w};
  *((bf16x4*)hb + i) = v;
}

// ---------------------------------------------------------------- Xh GEMM: out = x @ Wxh^T + b_h
__global__ __launch_bounds__(256) void k_gemm_xh(
    const bf16* __restrict__ xb, const bf16* __restrict__ wxh,
    const float* __restrict__ bh, float* __restrict__ out)
{
  __shared__ char As[16384];
  __shared__ char Bs[16384];
  const int bid = blockIdx.x;
  const int nt8 = bid & 7, mtb = bid >> 3;
  const int tid = threadIdx.x;
  const int lane = tid & 63, wv = tid >> 6;
  const int l15 = lane & 15, q = lane >> 4;
  const int wm = wv >> 1, wn = wv & 1;
  f32x4 acc[4][4] = {};
  const char* Ab = (const char*)(xb + (size_t)mtb*128*DD);
  const char* Bb = (const char*)(wxh + (size_t)nt8*128*DD);
  const int crow = tid >> 3, ccb = (tid & 7)*16;
  const int cdst = crow*128 + (ccb ^ ((crow & 7) << 4));
  for (int kt = 0; kt < 8; ++kt) {
    __syncthreads();
    #pragma unroll
    for (int i = 0; i < 4; ++i) {
      *(uint4*)(As + cdst + i*4096) = *(const uint4*)(Ab + (size_t)(crow + i*32)*1024 + kt*128 + ccb);
      *(uint4*)(Bs + cdst + i*4096) = *(const uint4*)(Bb + (size_t)(crow + i*32)*1024 + kt*128 + ccb);
    }
    __syncthreads();
    #pragma unroll
    for (int ks = 0; ks < 2; ++ks) {
      bf16x8 af[4], bfr[4];
      #pragma unroll
      for (int m4 = 0; m4 < 4; ++m4) {
        int row = wm*64 + m4*16 + l15, cb = ks*64 + 16*q;
        af[m4] = *(const bf16x8*)(As + row*128 + (cb ^ ((row&7)<<4)));
      }
      #pragma unroll
      for (int n4 = 0; n4 < 4; ++n4) {
        int row = wn*64 + n4*16 + l15, cb = ks*64 + 16*q;
        bfr[n4] = *(const bf16x8*)(Bs + row*128 + (cb ^ ((row&7)<<4)));
      }
      #pragma unroll
      for (int m4 = 0; m4 < 4; ++m4)
        #pragma unroll
        for (int n4 = 0; n4 < 4; ++n4)
          acc[m4][n4] = __builtin_amdgcn_mfma_f32_16x16x32_bf16(af[m4], bfr[n4], acc[m4][n4], 0, 0, 0);
    }
  }
  const int jb = nt8*128 + wn*64;
  const size_t mb = (size_t)mtb*128 + wm*64;
  #pragma unroll
  for (int n4 = 0; n4 < 4; ++n4) {
    int j = jb + n4*16 + l15;
    float bias = bh[j];
    #pragma unroll
    for (int m4 = 0; m4 < 4; ++m4)
      #pragma unroll
      for (int e = 0; e < 4; ++e) {
        size_t m = mb + m4*16 + 4*q + e;
        out[m*HH + j] = acc[m4][n4][e] + bias;
      }
  }
}

// ---------------------------------------------------------------- recurrent kernel
// 256 blocks x 512 threads; group g = bid&7 = one XCD (vote-verified).
// BALANCED column split: block sb computes z-cols [sb*32,+32) (its OWN
// phase-2 slice -> z kept in LDS, no global round trip) AND r-cols
// [sb*32,+32) (rh exchanged via L2). Every block identical work (skew fix).
// Waves: ch=0 -> z cols, ch=1 -> r cols; kh = K quarter; LDS reduce joins.
struct Frags { bf16x8 zr[4][2]; bf16x8 h[8]; };

template<int L>
__device__ __forceinline__ void tloop(const Frags& F, char* ldsW, char* scr, float* zsL,
    const bf16* __restrict__ xb, float* __restrict__ out,
    bf16* __restrict__ hb, bf16* __restrict__ rhb,
    unsigned* cnt1A, unsigned* cnt2A, unsigned char* flg1, unsigned char* flg2,
    int voteok, int g, int sb, int ch, int kh, int tid, int lane, int wv,
    const float (&bias)[2], float (&hreg)[4])
{
  const int l15 = lane & 15, q = lane >> 4;
  const bf16* hrow = hb  + (size_t)(g*16 + l15)*HH;
  const bf16* rrow = rhb + (size_t)(g*16 + l15)*HH;
  const int kh384 = kh*384, kh256 = kh*256;
  const int jown = sb*32 + ch*16 + l15;
  int use_local = L ? voteok : 0;

  for (int t = 0; t < LT; ++t) {
    // ---------------- phase 1: z (ch0) + r (ch1) preacts, K=1536 ----------------
    {
      f32x4 ab[12];
      const bf16* xrow = xb + (size_t)(t*BB + g*16 + l15)*DD;
      #pragma unroll
      for (int kk = 0; kk < 12; ++kk) {
        int kabs = kh384 + kk*32;
        if (kabs < HH) ab[kk] = ld16s<L>(hrow + kabs + 8*q);               // coherent
        else           ab[kk] = *(const f32x4*)(xrow + (kabs - HH) + 8*q); // plain cached
      }
      unsigned hv[2][4];
      if (ch == 1 && kh == 0) {            // r wave: cross-block h for r*h
        #pragma unroll
        for (int nt = 0; nt < 2; ++nt) {
          int cr = sb*32 + nt*16 + l15;
          #pragma unroll
          for (int e = 0; e < 4; ++e)
            hv[nt][e] = ld2s<L>(hb + (size_t)(g*16 + 4*q + e)*HH + cr);
        }
      }
      WAIT_VM0(); SCHED0();
      f32x4 a0 = {}, a1 = {};
      #pragma unroll
      for (int kk = 0; kk < 12; ++kk) {
        bf16x8 a = __builtin_bit_cast(bf16x8, ab[kk]);
        bf16x8 b0, b1;
        if (kk < 8) {
          b0 = *(const bf16x8*)(ldsW + (ch*32      + l15)*2064 + kh*512 + kk*64 + 16*q);
          b1 = *(const bf16x8*)(ldsW + (ch*32 + 16 + l15)*2064 + kh*512 + kk*64 + 16*q);
        } else { b0 = F.zr[kk-8][0]; b1 = F.zr[kk-8][1]; }
        a0 = __builtin_amdgcn_mfma_f32_16x16x32_bf16(a, b0, a0, 0, 0, 0);
        a1 = __builtin_amdgcn_mfma_f32_16x16x32_bf16(a, b1, a1, 0, 0, 0);
      }
      if (kh) {
        int s = ((kh-1)*2 + ch)*2;
        *(f32x4*)(scr + (s+0)*1024 + lane*16) = a0;
        *(f32x4*)(scr + (s+1)*1024 + lane*16) = a1;
      }
      __syncthreads();
      if (kh == 0) {
        #pragma unroll
        for (int k2 = 0; k2 < 3; ++k2) {
          int s = (k2*2 + ch)*2;
          a0 += *(const f32x4*)(scr + (s+0)*1024 + lane*16);
          a1 += *(const f32x4*)(scr + (s+1)*1024 + lane*16);
        }
        if (ch == 0) {                       // z wave -> LDS (block-local!)
          #pragma unroll
          for (int nt = 0; nt < 2; ++nt) {
            f32x4 ac = nt ? a1 : a0;
            #pragma unroll
            for (int e = 0; e < 4; ++e)
              zsL[(nt*16 + l15)*16 + 4*q + e] =
                1.f/(1.f + __expf(-(ac[e] + bias[nt])));
          }
        } else {                             // r wave -> rh to L2
          #pragma unroll
          for (int nt = 0; nt < 2; ++nt) {
            f32x4 ac = nt ? a1 : a0;
            int cr = sb*32 + nt*16 + l15;
            #pragma unroll
            for (int e = 0; e < 4; ++e) {
              int m = g*16 + 4*q + e;
              float gate = 1.f/(1.f + __expf(-(ac[e] + bias[nt])));
              st2s<L>(rhb + (size_t)m*HH + cr, bf16_bits(gate * bits_to_f32(hv[nt][e])));
            }
          }
        }
      }
    }
    bar_sync(cnt1A, flg1 + t*32, t, L ? voteok : 0, use_local,
             32u*(unsigned)(t+1), tid, lane, wv, sb);
    // ---------------- phase 2: h_tilde + combine, K=1024 ----------------
    {
      f32x4 rb[8];
      #pragma unroll
      for (int kk = 0; kk < 8; ++kk)
        rb[kk] = ld16s<L>(rrow + kh256 + kk*32 + 8*q);
      float xh[4];
      if (kh == 0) {
        #pragma unroll
        for (int e = 0; e < 4; ++e)
          xh[e] = out[(size_t)t*(BB*HH) + (size_t)(g*16 + 4*q + e)*HH + jown]; // plain: Xh+b_h
      }
      WAIT_VM0(); SCHED0();
      f32x4 acc = {};
      #pragma unroll
      for (int kk = 0; kk < 8; ++kk)
        acc = __builtin_amdgcn_mfma_f32_16x16x32_bf16(
            __builtin_bit_cast(bf16x8, rb[kk]), F.h[kk], acc, 0, 0, 0);
      if (kh) *(f32x4*)(scr + ((kh-1)*2 + ch)*1024 + lane*16) = acc;
      __syncthreads();
      if (kh == 0) {
        #pragma unroll
        for (int k2 = 0; k2 < 3; ++k2)
          acc += *(const f32x4*)(scr + (k2*2 + ch)*1024 + lane*16);
        f32x4 zv = *(const f32x4*)(zsL + (ch*16 + l15)*16 + 4*q);   // z from LDS
        #pragma unroll
        for (int e = 0; e < 4; ++e) {
          int m = g*16 + 4*q + e;
          size_t idx = (size_t)m*HH + jown;
          size_t oidx = (size_t)t*(BB*HH) + idx;
          float ht = tanhf(acc[e] + xh[e]);
          float hn = hreg[e] + zv[e]*(ht - hreg[e]);
          out[oidx] = hn;                    // plain store (block-private slot)
          hreg[e] = hn;
          st2s<L>(hb + idx, bf16_bits(hn));  // next step's h
        }
      }
    }
    bar_sync(cnt2A, flg2 + t*32, t, L ? voteok : 0, use_local,
             32u*(unsigned)(t+1), tid, lane, wv, sb);
    // self-clear my own t+2 flag bytes (single writer; ordered via drains+barriers)
    if (L && tid == 0 && voteok && t + 2 < LT) {
      st_flag(flg1 + (t+2)*32 + sb, 0u);
      st_flag(flg2 + (t+2)*32 + sb, 0u);
    }
  }
}

__global__ __launch_bounds__(512) void k_gru(
    const bf16* __restrict__ Wzr, const bf16* __restrict__ Whr,
    const bf16* __restrict__ xb, const float* __restrict__ h0,
    const float* __restrict__ bz, const float* __restrict__ br,
    float* __restrict__ out,
    bf16* __restrict__ hb, bf16* __restrict__ rhb,
    unsigned* __restrict__ bar, unsigned char* __restrict__ flg)
{
  extern __shared__ char smem[];
  char*  ldsW = smem;                         // 64 rows x 2064B weight slab
  char*  scr  = smem + 132096;                // 12KB kh-reduce scratch
  float* zsL  = (float*)(smem + 144384);      // 2KB z gate [32 cols][16 rows]
  volatile int* modep = (volatile int*)(smem + 146432);

  const int tid = threadIdx.x, bid = blockIdx.x;
  const int lane = tid & 63, wv = tid >> 6;
  const int l15 = lane & 15, q = lane >> 4;
  const int g = bid & 7, sb = bid >> 3;
  const int ch = wv & 1, kh = wv >> 1;
  unsigned* grp   = bar + (size_t)g*2048;
  unsigned* cnt1A = grp + 40;
  unsigned* cnt2A = grp + 48;
  unsigned char* flg1 = flg + (size_t)g*32768;
  unsigned char* flg2 = flg + (size_t)g*32768 + 16384;

  // stage LDS weights: rows 0..31 = W_z[sb*32..+32), rows 32..63 = W_r[sb*32..+32)
  #pragma unroll
  for (int i = 0; i < 16; ++i) {
    int ci = tid + i*512;
    int row = ci >> 7, c = ci & 127;
    int le = c*8, khs = le >> 8, rem = le & 255;
    int gr = (row < 32) ? sb*32 + row : HH + sb*32 + (row - 32);
    *(uint4*)(ldsW + row*2064 + c*16) =
      *(const uint4*)(Wzr + (size_t)gr*HD + khs*384 + rem);
  }
  Frags F;
  #pragma unroll
  for (int i = 0; i < 4; ++i)
    #pragma unroll
    for (int nt = 0; nt < 2; ++nt)
      F.zr[i][nt] = *(const bf16x8*)(Wzr
          + (size_t)((ch ? HH : 0) + sb*32 + nt*16 + l15)*HD
          + kh*384 + (8+i)*32 + 8*q);
  #pragma unroll
  for (int kk = 0; kk < 8; ++kk)
    F.h[kk] = *(const bf16x8*)(Whr + (size_t)(sb*32 + ch*16 + l15)*HH + kh*256 + kk*32 + 8*q);

  float bias[2];
  #pragma unroll
  for (int nt = 0; nt < 2; ++nt) {
    int c = sb*32 + nt*16 + l15;
    bias[nt] = (ch == 0) ? bz[c] : br[c];
  }
  float hreg[4];
  const int jown = sb*32 + ch*16 + l15;
  #pragma unroll
  for (int e = 0; e < 4; ++e)
    hreg[e] = h0[(size_t)(g*16 + 4*q + e)*HH + jown];

  // XCD vote (bounded; perf-only — IF fallback always correct)
  if (tid == 0) {
    int xcc;
    asm("s_getreg_b32 %0, hwreg(HW_REG_XCC_ID)" : "=s"(xcc));
    __hip_atomic_store(&grp[sb], (unsigned)(xcc + 1), __ATOMIC_RELAXED, __HIP_MEMORY_SCOPE_AGENT);
    unsigned first = 0; int ok = 1;
    long budget = 200000;
    for (int i = 0; i < 32; ++i) {
      unsigned v = 0;
      while (budget > 0) {
        v = __hip_atomic_load(&grp[i], __ATOMIC_RELAXED, __HIP_MEMORY_SCOPE_AGENT);
        if (v) break;
        --budget; __builtin_amdgcn_s_sleep(8);
      }
      if (!v) { ok = 0; break; }
      if (i == 0) first = v;
      else if (v != first) { ok = 0; break; }
    }
    *modep = ok;
  }
  __syncthreads();   // also covers LDS weight staging
  int voteok = *modep;

  if (voteok) tloop<1>(F, ldsW, scr, zsL, xb, out, hb, rhb, cnt1A, cnt2A,
                       flg1, flg2, 1, g, sb, ch, kh, tid, lane, wv, bias, hreg);
  else        tloop<0>(F, ldsW, scr, zsL, xb, out, hb, rhb, cnt1A, cnt2A,
                       flg1, flg2, 0, g, sb, ch, kh, tid, lane, wv, bias, hreg);
}

// ---------------------------------------------------------------- launch
extern "C" void kernel_launch(void* const* d_in, const int* in_sizes, int n_in,
                              void* d_out, int out_size, void* d_ws, size_t ws_size,
                              hipStream_t stream) {
  const float* x  = (const float*)d_in[0];
  const float* h0 = (const float*)d_in[1];
  const float* Wz = (const float*)d_in[2];
  const float* bz = (const float*)d_in[3];
  const float* Wr = (const float*)d_in[4];
  const float* br = (const float*)d_in[5];
  const float* Wh = (const float*)d_in[6];
  const float* bh = (const float*)d_in[7];
  float* out = (float*)d_out;
  char* ws = (char*)d_ws;
  if (ws_size < (size_t)WS_NEED) return;

  bf16*  wzr  = (bf16*) (ws + O_WZR);
  bf16*  whr  = (bf16*) (ws + O_WHR);
  bf16*  wxh  = (bf16*) (ws + O_WXH);
  bf16*  xbb  = (bf16*) (ws + O_XB);
  bf16*  hb   = (bf16*) (ws + O_HB);
  bf16*  rhb  = (bf16*) (ws + O_RHB);
  unsigned* bar = (unsigned*)(ws + O_BAR);
  unsigned char* flg = (unsigned char*)(ws + O_FLG);

  hipMemsetAsync(bar, 0, 65536, stream);  // vote slots + IF counters (flags self-clear)
  k_cvt<<<16384, 256, 0, stream>>>(x, xbb, MT*DD/8);
  k_cvt<<<768, 256, 0, stream>>>(Wz, wzr, HH*HD/8);
  k_cvt<<<768, 256, 0, stream>>>(Wr, wzr + (size_t)HH*HD, HH*HD/8);
  k_split_wh<<<768, 256, 0, stream>>>(Wh, whr, wxh);
  k_init_h<<<128, 256, 0, stream>>>(h0, hb);
  k_gemm_xh<<<4096, 256, 0, stream>>>(xbb, wxh, bh, out);

  hipFuncSetAttribute((const void*)k_gru, hipFuncAttributeMaxDynamicSharedMemorySize, 146448);
  k_gru<<<256, 512, 146448, stream>>>(wzr, whr, xbb, h0, bz, br, out, hb, rhb, bar, flg);
}